// Round 5
// baseline (1278.694 us; speedup 1.0000x reference)
//
#include <hip/hip_runtime.h>

// Problem constants
#define BB    512
#define TT    300
#define DD    128
#define HH    256
#define GG    1024      // 4*H
#define DNS   256
#define NC    14
#define KDIM  76800     // T*H

typedef _Float16 f16;
typedef _Float16 f16x8 __attribute__((ext_vector_type(8)));
typedef float    f32x4 __attribute__((ext_vector_type(4)));
typedef unsigned long long u64;

__device__ __forceinline__ float sigf(float x){ return 1.0f / (1.0f + __expf(-x)); }
__device__ __forceinline__ float tanhfast(float x){ return 2.0f / (1.0f + __expf(-2.0f*x)) - 1.0f; }

// ---------------- K1: embedding gather, fp32 -> fp16 x[B][T][D] ----------------
__global__ void k_gather(const int* __restrict__ idx, const float* __restrict__ emb,
                         f16* __restrict__ xbuf)
{
    int gid = blockIdx.x * 256 + threadIdx.x;       // one 4-dim chunk
    if (gid >= BB*TT*DD/4) return;
    int bt = gid >> 5;                              // 32 chunks per 128-dim row
    int c4 = gid & 31;
    int v  = idx[bt];
    const float4 e = *(const float4*)(emb + (size_t)v*DD + c4*4);
    union { f16 h[4]; uint2 u; } o;
    o.h[0]=(f16)e.x; o.h[1]=(f16)e.y; o.h[2]=(f16)e.z; o.h[3]=(f16)e.w;
    *(uint2*)(xbuf + (size_t)bt*DD + c4*4) = o.u;
}

// ---------------- K2: persistent LSTM recurrence ----------------
// R12: degree-1 exchange at R7's PROVEN register pressure.
// 64 blocks x 1024 threads (16 waves) = 32 batch-groups (16 rows) x 2 slots
// (128 h-dims = 512 gate rows). Wave owns 2 n-tiles -> bf[2][12] = 96 W-VGPRs
// per lane, IDENTICAL per-lane footprint to the verified R7 kernel (104-108
// total); __launch_bounds__(1024,4) enforces <=128 VGPR so 16 waves/CU fit.
// (R10/R11's 512-thr/192-W-VGPR variant failed twice at the harness level —
// suspected VGPR-cap infeasibility; this kills that hypothesis structurally.)
// M=16 full MFMA tiles (R7 wasted half of M) -> device MFMA work halves.
// Exchange: tagged words ((t<<16)|f16), relaxed agent atomics, NO fences
// (R8 lesson: release/acquire forces L2 writeback/invalidate storms).
// Thread-paired: consumer thread tid polls exactly ONE u64 (2 dims, 8B
// aligned) that peer-block thread tid publishes as ONE u64 (identical
// mapping both sides), issued jointly (R9 lesson: sequential spins cost N
// round trips). Depth-2 ping-pong race-free: producer reaches t+2 only
// after consuming h(t+1), which the peer publishes only after consuming
// h(t); each block publishes t-1 before polling t-1 -> no deadlock.
// Blocks b, b+32 -> same XCD under round-robin dispatch (heuristic only).
__global__ __launch_bounds__(1024, 4) void k_lstm(
    const f16* __restrict__ xbuf, f16* __restrict__ hs,
    const float* __restrict__ Wih, const float* __restrict__ Whh,
    const float* __restrict__ bih, const float* __restrict__ bhh,
    unsigned int* hpp)
{
    __shared__ f16   Ast[16*392];    // 16 rows x (256 h | 128 x | 8 pad)
    __shared__ float gbuf[16*516];   // gates [m][q], q = 4*d_local+ty, pad 516
    __shared__ float biasS[512];

    const int tid  = threadIdx.x;
    const int grp  = blockIdx.x & 31;               // batch-group: rows grp*16..+15
    const int slt  = blockIdx.x >> 5;               // slot 0..1 (same-XCD pairing)
    const int r0   = grp*16, j0 = slt*128;
    const int fb   = 128 - j0;                      // foreign slot dim base
    const int wv   = tid >> 6, lane = tid & 63;
    const int q16  = lane & 15, quad = lane >> 4;

    // ---- resident W fragments: wave wv owns n-tiles {2wv, 2wv+1} ----
    f16x8 bf[2][12];
    #pragma unroll
    for (int nt = 0; nt < 2; ++nt) {
        const int ql   = (wv*2 + nt)*16 + q16;      // local gate 0..511
        const int dl   = ql >> 2, ty = ql & 3;      // q = 4*d_local + ty
        const int Grow = ty*HH + j0 + dl;           // global gate row
        const float* wh = Whh + (size_t)Grow*HH;
        #pragma unroll
        for (int kk = 0; kk < 8; ++kk) {
            const float* p = wh + kk*32 + quad*8;
            float4 f0 = *(const float4*)p, f1 = *(const float4*)(p+4);
            f16x8 b;
            b[0]=(f16)f0.x; b[1]=(f16)f0.y; b[2]=(f16)f0.z; b[3]=(f16)f0.w;
            b[4]=(f16)f1.x; b[5]=(f16)f1.y; b[6]=(f16)f1.z; b[7]=(f16)f1.w;
            bf[nt][kk] = b;
        }
        const float* wi = Wih + (size_t)Grow*DD;
        #pragma unroll
        for (int kk = 0; kk < 4; ++kk) {
            const float* p = wi + kk*32 + quad*8;
            float4 f0 = *(const float4*)p, f1 = *(const float4*)(p+4);
            f16x8 b;
            b[0]=(f16)f0.x; b[1]=(f16)f0.y; b[2]=(f16)f0.z; b[3]=(f16)f0.w;
            b[4]=(f16)f1.x; b[5]=(f16)f1.y; b[6]=(f16)f1.z; b[7]=(f16)f1.w;
            bf[nt][8+kk] = b;
        }
    }
    if (tid < 512) {   // bias for local gate q = tid
        const int d = tid >> 2, ty = tid & 3;
        biasS[tid] = bih[ty*HH + j0 + d] + bhh[ty*HH + j0 + d];
    }

    // elementwise / exchange mapping: thread owns (row em, dims 2el, 2el+1)
    const int em = tid >> 6;                         // 0..15 (== wv)
    const int el = tid & 63;                         // 0..63
    float c0 = 0.f, c1 = 0.f;                        // cell state

    // zero-init h region of Ast (rows 0..15, dims 0..255); visible at syncA(t=0)
    {
        uint2 z = {0u,0u};
        *(uint2*)(Ast + (size_t)em*392 + el*4) = z;
    }

    // x-prefetch registers (tid<256): x(t) resident before step t starts
    const int xrow = tid >> 4, xch = tid & 15;
    uint4 xreg;
    if (tid < 256)
        xreg = *(const uint4*)(xbuf + ((size_t)(r0+xrow)*TT + 0)*DD + xch*8);

    for (int t = 0; t < TT; ++t) {
        // ---- stage x_t from registers (zero latency), prefetch x_{t+1} ----
        if (tid < 256) {
            *(uint4*)(Ast + (size_t)xrow*392 + 256 + xch*8) = xreg;
            if (t + 1 < TT)
                xreg = *(const uint4*)(xbuf + ((size_t)(r0+xrow)*TT + (t+1))*DD + xch*8);
        }
        // ---- stage foreign h_{t-1}: joint poll of this thread's ONE u64 ----
        if (t > 0) {
            const unsigned tgt = (unsigned)(t-1);
            const u64* pb = (const u64*)(hpp + (size_t)((t-1)&1)*BB*HH
                                             + (size_t)(r0+em)*HH + fb + el*2);
            u64 v;
            for (;;) {
                v = __hip_atomic_load(pb, __ATOMIC_RELAXED, __HIP_MEMORY_SCOPE_AGENT);
                unsigned t0 = ((unsigned)(v >> 16)) & 0xFFFFu;
                unsigned t1 = (unsigned)(v >> 48);
                if ((t0==tgt) & (t1==tgt)) break;
                __builtin_amdgcn_s_sleep(1);
            }
            union { f16 h[2]; unsigned u; } fo;
            union { unsigned short us; f16 hf; } w0, w1;
            w0.us = (unsigned short)v;
            w1.us = (unsigned short)(v >> 32);
            fo.h[0]=w0.hf; fo.h[1]=w1.hf;
            *(unsigned*)(Ast + (size_t)em*392 + fb + el*2) = fo.u;
            // own 128 dims already in Ast (written by elementwise at t-1)
        }
        __syncthreads();   // syncA: Ast complete (h 256 + x 128)

        // ---- gates[m][q] = sum_k A[m,k] * W[q,k]; wave = 2 n-tiles, M=16 ----
        f32x4 acc0 = {0.f,0.f,0.f,0.f}, acc1 = {0.f,0.f,0.f,0.f};
        const f16* arow = Ast + q16*392 + quad*8;
        #pragma unroll
        for (int kk = 0; kk < 12; ++kk) {
            f16x8 a = *(const f16x8*)(arow + kk*32);
            acc0 = __builtin_amdgcn_mfma_f32_16x16x32_f16(a, bf[0][kk], acc0, 0, 0, 0);
            acc1 = __builtin_amdgcn_mfma_f32_16x16x32_f16(a, bf[1][kk], acc1, 0, 0, 0);
        }
        // D layout: col=lane&15 -> q within tile, row=quad*4+r -> m
        #pragma unroll
        for (int r = 0; r < 4; ++r) {
            gbuf[(quad*4+r)*516 + (wv*2+0)*16 + q16] = acc0[r];
            gbuf[(quad*4+r)*516 + (wv*2+1)*16 + q16] = acc1[r];
        }
        __syncthreads();   // syncB: gates ready (all Ast reads of step t done)

        // ---- elementwise LSTM cell: (row em, dims 2el, 2el+1) ----
        const float* gb = gbuf  + (size_t)em*516 + el*8;
        const float* bb = biasS + el*8;
        union { f16 h[2]; unsigned u; } ho;
        unsigned pub0, pub1;
        {
            union { unsigned short us; f16 hf; } hu;
            float4 g, bs; float iv, fv, gv, ov, h;
            g = *(const float4*)(gb + 0);  bs = *(const float4*)(bb + 0);
            iv=sigf(g.x+bs.x); fv=sigf(g.y+bs.y); gv=tanhfast(g.z+bs.z); ov=sigf(g.w+bs.w);
            c0 = fv*c0 + iv*gv; h = ov*tanhfast(c0);
            hu.hf=(f16)h; ho.h[0]=hu.hf; pub0=((unsigned)t<<16)|hu.us;
            g = *(const float4*)(gb + 4);  bs = *(const float4*)(bb + 4);
            iv=sigf(g.x+bs.x); fv=sigf(g.y+bs.y); gv=tanhfast(g.z+bs.z); ov=sigf(g.w+bs.w);
            c1 = fv*c1 + iv*gv; h = ov*tanhfast(c1);
            hu.hf=(f16)h; ho.h[1]=hu.hf; pub1=((unsigned)t<<16)|hu.us;
        }
        // publish first (tagged words: validity travels with data), ONE u64
        u64* ob = (u64*)(hpp + (size_t)(t&1)*BB*HH + (size_t)(r0+em)*HH + j0 + el*2);
        u64 p01 = ((u64)pub1 << 32) | (u64)pub0;
        __hip_atomic_store(ob, p01, __ATOMIC_RELAXED, __HIP_MEMORY_SCOPE_AGENT);
        // own slice -> Ast for step t+1 (no fabric round-trip)
        *(unsigned*)(Ast + (size_t)em*392 + j0 + el*2) = ho.u;
        // hs for the dense layer: plain cached store, off the critical path
        *(unsigned*)(hs + ((size_t)(r0+em)*TT + t)*HH + j0 + el*2) = ho.u;
        // no third barrier: next step's Ast writes hit regions whose readers
        // finished before syncB; publishes are per-word self-validating.
    }
}

// ---------------- K3: dense GEMM, split-K -> partials ----------------
// A = hs (fp16), B = W3 (fp32, converted to fp16 during LDS staging -> no
// separate 236MB convert pass). dens[m][n] = sum_k hs[m,k]*W3[n,k].
__global__ __launch_bounds__(256) void k_dense(
    const f16* __restrict__ hs, const float* __restrict__ W3, float* __restrict__ part)
{
    __shared__ f16 Ap[128*40];
    __shared__ f16 Bp[128*40];
    const int tid = threadIdx.x;
    const int kb = blockIdx.x & 31, tn = (blockIdx.x >> 5) & 1, tm = blockIdx.x >> 6;
    const int m0 = tm*128, n0 = tn*128;
    const long k0 = (long)kb * 2400;
    const int wv = tid >> 6, lane = tid & 63, q16 = lane & 15, quad = lane >> 4;

    f32x4 acc[2][8];
    #pragma unroll
    for (int a = 0; a < 2; ++a)
        #pragma unroll
        for (int b = 0; b < 8; ++b) acc[a][b] = (f32x4){0.f,0.f,0.f,0.f};

    for (int ks = 0; ks < 75; ++ks) {
        const long kbase = k0 + ks*32;
        #pragma unroll
        for (int rep = 0; rep < 4; ++rep) {
            int cid = tid + rep*256;                 // 1024 chunks: 512 A + 512 B
            int rrow = (cid & 511) >> 2;
            int c4   = cid & 3;
            if (cid < 512) {
                const f16* src = hs + (size_t)(m0+rrow)*KDIM + kbase + c4*8;
                *(uint4*)(Ap + rrow*40 + c4*8) = *(const uint4*)src;
            } else {
                const float* src = W3 + (size_t)(n0+rrow)*KDIM + kbase + c4*8;
                float4 f0 = *(const float4*)src, f1 = *(const float4*)(src+4);
                union { f16 h[8]; uint4 u; } o;
                o.h[0]=(f16)f0.x; o.h[1]=(f16)f0.y; o.h[2]=(f16)f0.z; o.h[3]=(f16)f0.w;
                o.h[4]=(f16)f1.x; o.h[5]=(f16)f1.y; o.h[6]=(f16)f1.z; o.h[7]=(f16)f1.w;
                *(uint4*)(Bp + rrow*40 + c4*8) = o.u;
            }
        }
        __syncthreads();

        f16x8 a0 = *(const f16x8*)(Ap + ((wv*2+0)*16 + q16)*40 + quad*8);
        f16x8 a1 = *(const f16x8*)(Ap + ((wv*2+1)*16 + q16)*40 + quad*8);
        #pragma unroll
        for (int ns = 0; ns < 8; ++ns) {
            f16x8 b = *(const f16x8*)(Bp + (ns*16 + q16)*40 + quad*8);
            acc[0][ns] = __builtin_amdgcn_mfma_f32_16x16x32_f16(a0, b, acc[0][ns], 0,0,0);
            acc[1][ns] = __builtin_amdgcn_mfma_f32_16x16x32_f16(a1, b, acc[1][ns], 0,0,0);
        }
        __syncthreads();
    }
    #pragma unroll
    for (int ms = 0; ms < 2; ++ms)
        #pragma unroll
        for (int ns = 0; ns < 8; ++ns)
            #pragma unroll
            for (int r = 0; r < 4; ++r) {
                int m = m0 + (wv*2+ms)*16 + quad*4 + r;
                int n = n0 + ns*16 + q16;
                part[(size_t)kb*BB*DNS + (size_t)m*DNS + n] = acc[ms][ns][r];
            }
}

// ---------------- K4: reduce split-K partials + bias + relu ----------------
__global__ void k_reduce(const float* __restrict__ part, const float* __restrict__ b3,
                         float* __restrict__ dens)
{
    int g = blockIdx.x * 256 + threadIdx.x;
    if (g >= BB*DNS) return;
    int n = g & 255;
    float s = b3[n];
    #pragma unroll
    for (int kb = 0; kb < 32; ++kb) s += part[(size_t)kb*BB*DNS + g];
    dens[g] = fmaxf(s, 0.0f);
}

// ---------------- K5: final 256->14 + softmax ----------------
__global__ __launch_bounds__(64) void k_final(
    const float* __restrict__ dens, const float* __restrict__ W4,
    const float* __restrict__ b4, float* __restrict__ out)
{
    const int b = blockIdx.x, lane = threadIdx.x;
    const float4 dv = *(const float4*)(dens + (size_t)b*DNS + lane*4);
    float lg[NC];
    #pragma unroll
    for (int cc = 0; cc < NC; ++cc) {
        const float4 w = *(const float4*)(W4 + (size_t)cc*DNS + lane*4);
        float v = dv.x*w.x + dv.y*w.y + dv.z*w.z + dv.w*w.w;
        #pragma unroll
        for (int off = 32; off; off >>= 1) v += __shfl_xor(v, off, 64);
        lg[cc] = v + b4[cc];
    }
    if (lane == 0) {
        float m = lg[0];
        #pragma unroll
        for (int cc = 1; cc < NC; ++cc) m = fmaxf(m, lg[cc]);
        float e[NC], s = 0.f;
        #pragma unroll
        for (int cc = 0; cc < NC; ++cc) { e[cc] = __expf(lg[cc]-m); s += e[cc]; }
        const float inv = 1.0f/s;
        #pragma unroll
        for (int cc = 0; cc < NC; ++cc) out[(size_t)b*NC + cc] = e[cc]*inv;
    }
}

// ---------------- launch ----------------
extern "C" void kernel_launch(void* const* d_in, const int* in_sizes, int n_in,
                              void* d_out, int out_size, void* d_ws, size_t ws_size,
                              hipStream_t stream)
{
    const int*   idx = (const int*)  d_in[0];
    // d_in[1] = traj_lens: unused by the reference
    const float* emb = (const float*)d_in[2];
    const float* Wih = (const float*)d_in[3];
    const float* Whh = (const float*)d_in[4];
    const float* bih = (const float*)d_in[5];
    const float* bhh = (const float*)d_in[6];
    const float* W3  = (const float*)d_in[7];
    const float* b3  = (const float*)d_in[8];
    const float* W4  = (const float*)d_in[9];
    const float* b4  = (const float*)d_in[10];
    float* out = (float*)d_out;

    char* ws = (char*)d_ws;
    f16*   xbuf = (f16*)  (ws);                           // 39,321,600 B
    f16*   hs   = (f16*)  (ws + 39321600);                // 78,643,200 B
    float* part = (float*)(ws + 117964800);               // 16,777,216 B
    float* dens = (float*)(ws + 134742016);               //    524,288 B
    // hpp (tagged h ping-pong, 2x512x256 uint32 = 1 MB) aliases `part`:
    // used only during k_lstm; part written only afterwards by k_dense.
    // Tags self-validate (k_dense float partials' upper 16 bits are
    // exponent-laden, never 0..299 except exact-zero corner) -> no memset.
    unsigned int* hpp = (unsigned int*)part;

    k_gather<<<19200, 256, 0, stream>>>(idx, emb, xbuf);
    k_lstm  <<<64, 1024, 0, stream>>>(xbuf, hs, Wih, Whh, bih, bhh, hpp);
    k_dense <<<256, 256, 0, stream>>>(hs, W3, part);
    k_reduce<<<512, 256, 0, stream>>>(part, b3, dens);
    k_final <<<BB, 64, 0, stream>>>(dens, W4, b4, out);
}